// Round 1
// baseline (807.232 us; speedup 1.0000x reference)
//
#include <hip/hip_runtime.h>
#include <cstdint>
#include <cstddef>

#define TILE 64
#define KCH 64
#define LPAD 68          // LDS row stride in floats (64 + 4)
#define BINS 16384
#define POSCAP 256
#define CANDCAP 1024
#define NEG_K 50

__device__ __forceinline__ unsigned okey(float f) {
    unsigned u = __float_as_uint(f);
    return (u & 0x80000000u) ? ~u : (u | 0x80000000u);
}

__global__ __launch_bounds__(256) void setup_kernel(const int* __restrict__ index_labels,
                                                    const int* __restrict__ img_proxy_index,
                                                    const int* __restrict__ all_proxy_label,
                                                    int B, int* __restrict__ batch_lbl,
                                                    float* __restrict__ out) {
    int i = threadIdx.x;
    if (i == 0) out[0] = 0.0f;
    if (i < B) {
        int il = index_labels[i];
        int pidx = img_proxy_index[il];
        batch_lbl[i] = all_proxy_label[pidx];
    }
}

// scores[r_local, p] = 20 * dot(features[row_base + r_local, :], proxy[p, :])
__global__ __launch_bounds__(256) void gemm_kernel(const float* __restrict__ features,
                                                   const float* __restrict__ proxy,
                                                   float* __restrict__ scores,
                                                   int row_base, int rows_chunk,
                                                   int B, int P, int D) {
    __shared__ float As[TILE][LPAD];
    __shared__ float Bs[TILE][LPAD];

    int t  = threadIdx.x;
    int tx = t & 15;        // col group
    int ty = t >> 4;        // row group
    int p0 = blockIdx.x * TILE;
    int i0 = blockIdx.y * TILE;

    float acc[4][4];
#pragma unroll
    for (int i = 0; i < 4; i++)
#pragma unroll
        for (int j = 0; j < 4; j++) acc[i][j] = 0.0f;

    for (int kc = 0; kc < D; kc += KCH) {
        // stage A and B k-slices: 64 rows x 64 floats each = 1024 float4 each
#pragma unroll
        for (int j = 0; j < 4; j++) {
            int idx = j * 256 + t;          // 0..1023
            int r   = idx >> 4;             // 0..63
            int c4  = (idx & 15) << 2;      // 0,4,...,60

            float4 va = make_float4(0.f, 0.f, 0.f, 0.f);
            int gr = row_base + i0 + r;
            if ((i0 + r) < rows_chunk && gr < B)
                va = *reinterpret_cast<const float4*>(&features[(size_t)gr * D + kc + c4]);
            *reinterpret_cast<float4*>(&As[r][c4]) = va;

            float4 vb = make_float4(0.f, 0.f, 0.f, 0.f);
            int gp = p0 + r;
            if (gp < P)
                vb = *reinterpret_cast<const float4*>(&proxy[(size_t)gp * D + kc + c4]);
            *reinterpret_cast<float4*>(&Bs[r][c4]) = vb;
        }
        __syncthreads();

#pragma unroll
        for (int k4 = 0; k4 < KCH; k4 += 4) {
            float4 av[4], bv[4];
#pragma unroll
            for (int i = 0; i < 4; i++)
                av[i] = *reinterpret_cast<const float4*>(&As[ty + 16 * i][k4]);
#pragma unroll
            for (int j = 0; j < 4; j++)
                bv[j] = *reinterpret_cast<const float4*>(&Bs[tx + 16 * j][k4]);
#pragma unroll
            for (int i = 0; i < 4; i++)
#pragma unroll
                for (int j = 0; j < 4; j++) {
                    acc[i][j] += av[i].x * bv[j].x + av[i].y * bv[j].y
                               + av[i].z * bv[j].z + av[i].w * bv[j].w;
                }
        }
        __syncthreads();
    }

    const float scale = 20.0f;  // 1/TEMP
#pragma unroll
    for (int i = 0; i < 4; i++) {
        int r = i0 + ty + 16 * i;
        if (r >= rows_chunk) continue;
#pragma unroll
        for (int j = 0; j < 4; j++) {
            int p = p0 + tx + 16 * j;
            if (p < P) scores[(size_t)r * P + p] = acc[i][j] * scale;
        }
    }
}

// One block per row: exact top-k selection + loss contribution.
__global__ __launch_bounds__(256) void select_kernel(const float* __restrict__ scores,
                                                     const int* __restrict__ labels,
                                                     const int* __restrict__ batch_lbl,
                                                     int row_base, int P,
                                                     float* __restrict__ out, float invB) {
    __shared__ unsigned hist[BINS];
    __shared__ float pos_s[POSCAP];
    __shared__ int   pos_idx[POSCAP];
    __shared__ float cand[CANDCAP];
    __shared__ int   sh_posn, sh_candn, sh_bstar, sh_cumabove;
    __shared__ float red[256];
    __shared__ unsigned scan[256];

    int tid = threadIdx.x;
    int row = blockIdx.x;
    int g   = row_base + row;
    int mylbl = batch_lbl[g];
    const float* srow = scores + (size_t)row * P;

    for (int b = tid; b < BINS; b += 256) hist[b] = 0u;
    if (tid == 0) { sh_posn = 0; sh_candn = 0; sh_bstar = -1; sh_cumabove = 0; }
    __syncthreads();

    // ---- pass 1: positives -> list, negatives -> histogram + max ----
    float negmax = -3.0e38f;
    for (int p = tid; p < P; p += 256) {
        float s = srow[p];
        int lbl = labels[p];
        if (lbl == mylbl) {
            int n = atomicAdd(&sh_posn, 1);
            if (n < POSCAP) { pos_s[n] = s; pos_idx[n] = p; }
        } else {
            negmax = fmaxf(negmax, s);
            atomicAdd(&hist[okey(s) >> 18], 1u);
        }
    }
    __syncthreads();

    int pn   = sh_posn;
    int pcap = min(pn, POSCAP);

    float pmax = -3.0e38f;
    for (int n = tid; n < pcap; n += 256) pmax = fmaxf(pmax, pos_s[n]);
    red[tid] = fmaxf(negmax, pmax);
    __syncthreads();
    for (int off = 128; off > 0; off >>= 1) {
        if (tid < off) red[tid] = fmaxf(red[tid], red[tid + off]);
        __syncthreads();
    }
    float M = red[0];
    __syncthreads();   // protect red[] before reuse

    int q = min(pn, NEG_K);
    int m = NEG_K - q;

    // ---- find bin containing the m-th largest negative ----
    if (m > 0) {
        const int CB = BINS / 256;   // 64 bins per thread
        int base = tid * CB;
        unsigned csum = 0;
        for (int b = 0; b < CB; b++) csum += hist[base + b];
        scan[tid] = csum;
        __syncthreads();
        for (int off = 1; off < 256; off <<= 1) {
            unsigned v = (tid + off < 256) ? scan[tid + off] : 0u;
            __syncthreads();
            scan[tid] += v;
            __syncthreads();
        }
        unsigned cumExcl = (tid + 1 < 256) ? scan[tid + 1] : 0u;
        if (cumExcl < (unsigned)m && scan[tid] >= (unsigned)m) {
            unsigned cum = cumExcl;
            for (int b = CB - 1; b >= 0; b--) {
                unsigned c = hist[base + b];
                if (cum < (unsigned)m && cum + c >= (unsigned)m) {
                    sh_bstar = base + b;
                    sh_cumabove = (int)cum;
                    break;
                }
                cum += c;
            }
        }
        __syncthreads();
    }
    int bstar    = sh_bstar;
    int cumabove = sh_cumabove;

    // ---- pass 2: sum exp of strictly-above bins, collect boundary bin ----
    float sumexp = 0.0f;
    if (m > 0) {
        for (int p = tid; p < P; p += 256) {
            float s = srow[p];
            int lbl = labels[p];
            if (lbl == mylbl) continue;
            int bin = (int)(okey(s) >> 18);
            if (bin > bstar) {
                sumexp += expf(s - M);
            } else if (bin == bstar) {
                int n = atomicAdd(&sh_candn, 1);
                if (n < CANDCAP) cand[n] = s;
            }
        }
    }
    red[tid] = sumexp;
    __syncthreads();
    for (int off = 128; off > 0; off >>= 1) {
        if (tid < off) red[tid] += red[tid + off];
        __syncthreads();
    }

    // ---- wave 0: boundary-bin exact top-r, positives in index order ----
    float bsum = 0.0f, possum = 0.0f, posexp = 0.0f;
    if (tid < 64) {
        int lane = tid;
        if (m > 0) {
            int cn = min(sh_candn, CANDCAP);
            int r  = m - cumabove;
            if (r > cn) r = cn;
            for (int it = 0; it < r; it++) {
                float mx = -3.0e38f; int mi = -1;
                for (int c = lane; c < cn; c += 64) {
                    float v = cand[c];
                    if (v > mx) { mx = v; mi = c; }
                }
                for (int off = 32; off > 0; off >>= 1) {
                    float ox = __shfl_xor(mx, off);
                    int   oi = __shfl_xor(mi, off);
                    if (ox > mx || (ox == mx && oi >= 0 && (mi < 0 || oi < mi))) { mx = ox; mi = oi; }
                }
                if (lane == 0) bsum += expf(mx - M);
                if (mi >= 0) cand[mi] = -3.0e38f;
            }
        }
        // positives: q lowest indices (distinct indices -> unique argmin)
        for (int it = 0; it < q; it++) {
            int mn = 0x7fffffff; int mc = -1;
            for (int c = lane; c < pcap; c += 64) {
                int ix = pos_idx[c];
                if (ix < mn) { mn = ix; mc = c; }
            }
            for (int off = 32; off > 0; off >>= 1) {
                int on = __shfl_xor(mn, off);
                int oc = __shfl_xor(mc, off);
                if (on < mn) { mn = on; mc = oc; }
            }
            float s = (mc >= 0) ? pos_s[mc] : 0.0f;
            if (lane == 0) { possum += s; posexp += expf(s - M); }
            if (mc >= 0) pos_idx[mc] = 0x7fffffff;
        }
    }
    __syncthreads();

    if (tid == 0) {
        float total = red[0] + bsum + posexp;
        float lse = M + logf(total);
        float npos = (float)max(pn, 1);
        float loss = ((float)q * lse - possum) / npos;
        atomicAdd(out, loss * invB);
    }
}

extern "C" void kernel_launch(void* const* d_in, const int* in_sizes, int n_in,
                              void* d_out, int out_size, void* d_ws, size_t ws_size,
                              hipStream_t stream) {
    const float* features       = (const float*)d_in[0];
    const int*   index_labels   = (const int*)d_in[1];
    const float* proxy          = (const float*)d_in[2];
    const int*   img_proxy_index= (const int*)d_in[3];
    const int*   all_proxy_label= (const int*)d_in[4];
    float* out = (float*)d_out;

    const int D = 256;
    const int B = in_sizes[0] / D;      // 256
    const int P = in_sizes[2] / D;      // 100000

    int*   batch_lbl = (int*)d_ws;
    float* scores    = (float*)((char*)d_ws + 1024);

    size_t avail  = (ws_size > 1024) ? ws_size - 1024 : 0;
    size_t perrow = (size_t)P * sizeof(float);
    size_t rmax   = perrow ? (avail / perrow) : 0;
    int R = (rmax >= (size_t)B) ? B : (int)rmax;
    if (R < 1) R = 1;

    setup_kernel<<<1, 256, 0, stream>>>(index_labels, img_proxy_index, all_proxy_label,
                                        B, batch_lbl, out);

    float invB = 1.0f / (float)B;
    for (int rb = 0; rb < B; rb += R) {
        int rc = (B - rb < R) ? (B - rb) : R;
        dim3 grid((P + TILE - 1) / TILE, (rc + TILE - 1) / TILE);
        gemm_kernel<<<grid, 256, 0, stream>>>(features, proxy, scores, rb, rc, B, P, D);
        select_kernel<<<rc, 256, 0, stream>>>(scores, all_proxy_label, batch_lbl, rb, P, out, invB);
    }
}

// Round 3
// 618.622 us; speedup vs baseline: 1.3049x; 1.3049x over previous
//
#include <hip/hip_runtime.h>
#include <cstdint>
#include <cstddef>

#define NEG_K 50
#define POSCAP 128
#define CANDCAP 1024
#define SLICE 8192
#define SBINS 4096
#define BNDCAP 192

typedef __attribute__((ext_vector_type(8))) short bf16x8;
typedef __attribute__((ext_vector_type(4))) float f32x4;

__device__ __forceinline__ unsigned okey(float f) {
    unsigned u = __float_as_uint(f);
    return (u & 0x80000000u) ? ~u : (u | 0x80000000u);
}
// fp32 -> bf16 round-to-nearest-even (inputs are finite)
__device__ __forceinline__ unsigned f2b(float x) {
    unsigned u = __float_as_uint(x);
    return (u + 0x7FFFu + ((u >> 16) & 1u)) >> 16;
}

__global__ __launch_bounds__(256) void setup_kernel(const int* __restrict__ il,
                                                    const int* __restrict__ ipi,
                                                    const int* __restrict__ apl,
                                                    int B, int* __restrict__ batch_lbl,
                                                    int* __restrict__ posn,
                                                    int* __restrict__ candn,
                                                    float* __restrict__ out) {
    int i = threadIdx.x;
    if (i == 0) out[0] = 0.0f;
    if (i < B) {
        batch_lbl[i] = apl[ipi[il[i]]];
        posn[i] = 0;
        candn[i] = 0;
    }
}

// scores[r, p] = 20 * dot(F[row_base+r,:], Pm[p,:])  via bf16 MFMA, fp32 accum.
// 128x128 tile, 4 waves (2x2), each wave 64x64 = 4x4 frags of 16x16x32.
__global__ __launch_bounds__(256) void gemm_bf16(const float* __restrict__ F,
                                                 const float* __restrict__ Pm,
                                                 float* __restrict__ scores,
                                                 int row_base, int rc, int B, int P) {
    const int D = 256;
    __shared__ char As[128 * 128];   // logical [row][64 bf16], byte o ^ ((row&7)<<4)
    __shared__ char Bs[128 * 128];

    int t = threadIdx.x;
    int l = t & 63;
    int w = t >> 6;
    int wr = w >> 1, wc = w & 1;
    int p0 = blockIdx.x * 128;
    int i0 = blockIdx.y * 128;

    f32x4 acc[4][4];
#pragma unroll
    for (int m = 0; m < 4; m++)
#pragma unroll
        for (int n = 0; n < 4; n++) acc[m][n] = (f32x4){0.f, 0.f, 0.f, 0.f};

    int sr = t >> 3;          // 0..31
    int sk = (t & 7) * 8;     // k element offset

    for (int kk = 0; kk < D; kk += 64) {
#pragma unroll
        for (int c = 0; c < 4; c++) {
            int r = c * 32 + sr;
            int ostore = (r * 128 + (t & 7) * 16) ^ ((r & 7) << 4);

            int gr = row_base + i0 + r; if (gr >= B) gr = B - 1;
            const float* fs = F + (size_t)gr * D + kk + sk;
            float4 a0 = *(const float4*)fs;
            float4 a1 = *(const float4*)(fs + 4);
            uint4 pa;
            pa.x = f2b(a0.x) | (f2b(a0.y) << 16);
            pa.y = f2b(a0.z) | (f2b(a0.w) << 16);
            pa.z = f2b(a1.x) | (f2b(a1.y) << 16);
            pa.w = f2b(a1.z) | (f2b(a1.w) << 16);
            *(uint4*)(As + ostore) = pa;

            int gp = p0 + r; if (gp >= P) gp = P - 1;
            const float* ps = Pm + (size_t)gp * D + kk + sk;
            float4 b0 = *(const float4*)ps;
            float4 b1 = *(const float4*)(ps + 4);
            uint4 pb;
            pb.x = f2b(b0.x) | (f2b(b0.y) << 16);
            pb.y = f2b(b0.z) | (f2b(b0.w) << 16);
            pb.z = f2b(b1.x) | (f2b(b1.y) << 16);
            pb.w = f2b(b1.z) | (f2b(b1.w) << 16);
            *(uint4*)(Bs + ostore) = pb;
        }
        __syncthreads();

#pragma unroll
        for (int s = 0; s < 2; s++) {
            bf16x8 af[4], bfr[4];
#pragma unroll
            for (int m = 0; m < 4; m++) {
                int rowa = wr * 64 + m * 16 + (l & 15);
                int kb = s * 64 + (l >> 4) * 16;
                af[m] = *(const bf16x8*)(As + ((rowa * 128 + kb) ^ ((rowa & 7) << 4)));
                int rowb = wc * 64 + m * 16 + (l & 15);
                bfr[m] = *(const bf16x8*)(Bs + ((rowb * 128 + kb) ^ ((rowb & 7) << 4)));
            }
#pragma unroll
            for (int m = 0; m < 4; m++)
#pragma unroll
                for (int n = 0; n < 4; n++)
                    acc[m][n] = __builtin_amdgcn_mfma_f32_16x16x32_bf16(af[m], bfr[n], acc[m][n], 0, 0, 0);
        }
        __syncthreads();
    }

#pragma unroll
    for (int m = 0; m < 4; m++) {
        int rbase = wr * 64 + m * 16 + ((l >> 4) << 2);
#pragma unroll
        for (int n = 0; n < 4; n++) {
            int p = p0 + wc * 64 + n * 16 + (l & 15);
            if (p < P) {
#pragma unroll
                for (int j = 0; j < 4; j++) {
                    int rr = i0 + rbase + j;
                    if (rr < rc) scores[(size_t)rr * P + p] = acc[m][n][j] * 20.0f;
                }
            }
        }
    }
}

// Phase A: per (slice, row) block: exact local top-50 negatives -> candidate
// superset (values) + positives (value, index) to global per-row lists.
__global__ __launch_bounds__(256) void selectA_kernel(const float* __restrict__ scores,
                                                      const int* __restrict__ labels,
                                                      const int* __restrict__ batch_lbl,
                                                      int row_base, int P,
                                                      int* __restrict__ posn,
                                                      float* __restrict__ posv,
                                                      int* __restrict__ posi,
                                                      int* __restrict__ candn,
                                                      float* __restrict__ cand) {
    __shared__ unsigned hist[SBINS];
    __shared__ unsigned ssum[256];
    __shared__ int sh_bstar;

    int tid = threadIdx.x;
    int row = blockIdx.y;
    int g = row_base + row;
    int mylbl = batch_lbl[g];
    int pbeg = blockIdx.x * SLICE;
    int pend = min(pbeg + SLICE, P);
    const float* srow = scores + (size_t)row * P;

    for (int b = tid; b < SBINS; b += 256) hist[b] = 0u;
    if (tid == 0) sh_bstar = 0;
    __syncthreads();

    for (int p = pbeg + tid; p < pend; p += 256) {
        float s = srow[p];
        int lbl = labels[p];
        if (lbl == mylbl) {
            int n = atomicAdd(&posn[g], 1);
            if (n < POSCAP) { posv[g * POSCAP + n] = s; posi[g * POSCAP + n] = p; }
        } else {
            atomicAdd(&hist[okey(s) >> 20], 1u);
        }
    }
    __syncthreads();

    unsigned sum16 = 0;
    int base = tid * (SBINS / 256);
#pragma unroll
    for (int b = 0; b < SBINS / 256; b++) sum16 += hist[base + b];
    ssum[tid] = sum16;
    __syncthreads();
    for (int off = 1; off < 256; off <<= 1) {
        unsigned v = (tid + off < 256) ? ssum[tid + off] : 0u;
        __syncthreads();
        ssum[tid] += v;
        __syncthreads();
    }
    unsigned total = ssum[0];
    unsigned target = min(total, (unsigned)NEG_K);

    if (target > 0) {
        unsigned above = (tid < 255) ? ssum[tid + 1] : 0u;
        if (ssum[tid] >= target && above < target) {
            unsigned cum = above;
            for (int b = base + SBINS / 256 - 1; b >= base; b--) {
                cum += hist[b];
                if (cum >= target) { sh_bstar = b; break; }
            }
        }
        __syncthreads();
        int bstar = sh_bstar;
        for (int p = pbeg + tid; p < pend; p += 256) {
            float s = srow[p];
            if ((int)(okey(s) >> 20) >= bstar) {
                int lbl = labels[p];
                if (lbl != mylbl) {
                    int n = atomicAdd(&candn[g], 1);
                    if (n < CANDCAP) cand[(size_t)g * CANDCAP + n] = s;
                }
            }
        }
    }
}

// Final: one block per row. Exact top-m over candidates, LSE (M=20), loss.
__global__ __launch_bounds__(256) void final_kernel(const int* __restrict__ posn,
                                                    const float* __restrict__ posv,
                                                    const int* __restrict__ posi,
                                                    const int* __restrict__ candn,
                                                    const float* __restrict__ cand,
                                                    float* __restrict__ out, int B) {
    __shared__ unsigned hist[SBINS];
    __shared__ unsigned ssum[256];
    __shared__ float red[256];
    __shared__ float bnd[BNDCAP];
    __shared__ float pv[POSCAP];
    __shared__ int pidx[POSCAP];
    __shared__ int sh_bstar, sh_cumabove, sh_bndn;
    __shared__ float w_bsum, w_ps, w_pe;

    int tid = threadIdx.x;
    int g = blockIdx.x;
    int pn = posn[g];
    int pcap = min(pn, POSCAP);
    int q = min(pn, NEG_K);
    int m = NEG_K - q;
    int cn = min(candn[g], CANDCAP);
    const float* crow = cand + (size_t)g * CANDCAP;

    for (int b = tid; b < SBINS; b += 256) hist[b] = 0u;
    if (tid == 0) {
        sh_bstar = SBINS; sh_cumabove = 0; sh_bndn = 0;
        w_bsum = 0.0f; w_ps = 0.0f; w_pe = 0.0f;
    }
    __syncthreads();

    if (m > 0) {
        for (int c = tid; c < cn; c += 256)
            atomicAdd(&hist[okey(crow[c]) >> 20], 1u);
    }
    __syncthreads();

    unsigned sum16 = 0;
    int base = tid * (SBINS / 256);
#pragma unroll
    for (int b = 0; b < SBINS / 256; b++) sum16 += hist[base + b];
    ssum[tid] = sum16;
    __syncthreads();
    for (int off = 1; off < 256; off <<= 1) {
        unsigned v = (tid + off < 256) ? ssum[tid + off] : 0u;
        __syncthreads();
        ssum[tid] += v;
        __syncthreads();
    }
    unsigned total = ssum[0];
    unsigned target = (m > 0) ? min(total, (unsigned)m) : 0u;
    if (target > 0) {
        unsigned above = (tid < 255) ? ssum[tid + 1] : 0u;
        if (ssum[tid] >= target && above < target) {
            unsigned cum = above;
            for (int b = base + SBINS / 256 - 1; b >= base; b--) {
                unsigned nc = cum + hist[b];
                if (nc >= target) { sh_bstar = b; sh_cumabove = (int)cum; break; }
                cum = nc;
            }
        }
    }
    __syncthreads();
    int bstar = sh_bstar;
    int cumabove = sh_cumabove;

    float se = 0.0f;
    if (m > 0) {
        for (int c = tid; c < cn; c += 256) {
            float s = crow[c];
            int bin = (int)(okey(s) >> 20);
            if (bin > bstar) se += expf(s - 20.0f);
            else if (bin == bstar) {
                int n = atomicAdd(&sh_bndn, 1);
                if (n < BNDCAP) bnd[n] = s;
            }
        }
    }
    red[tid] = se;
    for (int c = tid; c < pcap; c += 256) {
        pv[c] = posv[g * POSCAP + c];
        pidx[c] = posi[g * POSCAP + c];
    }
    __syncthreads();
    for (int off = 128; off > 0; off >>= 1) {
        if (tid < off) red[tid] += red[tid + off];
        __syncthreads();
    }
    float negexp_above = red[0];
    __syncthreads();

    // positives fast path (pn <= NEG_K): sum all positives
    float psum_p = 0.0f, pexp_p = 0.0f;
    if (pn <= NEG_K) {
        for (int c = tid; c < pcap; c += 256) {
            float v = pv[c];
            psum_p += v;
            pexp_p += expf(v - 20.0f);
        }
    }
    red[tid] = psum_p;
    __syncthreads();
    for (int off = 128; off > 0; off >>= 1) { if (tid < off) red[tid] += red[tid + off]; __syncthreads(); }
    float possum = red[0];
    __syncthreads();
    red[tid] = pexp_p;
    __syncthreads();
    for (int off = 128; off > 0; off >>= 1) { if (tid < off) red[tid] += red[tid + off]; __syncthreads(); }
    float posexp = red[0];
    __syncthreads();

    if (tid < 64) {
        int lane = tid;
        float bsum = 0.0f, ps = 0.0f, pe = 0.0f;
        if (m > 0) {
            int bn = min(sh_bndn, BNDCAP);
            int r = m - cumabove;
            if (r > bn) r = bn;
            for (int it = 0; it < r; it++) {
                float mx = -3.0e38f; int mi = -1;
                for (int c = lane; c < bn; c += 64) {
                    float v = bnd[c];
                    if (v > mx) { mx = v; mi = c; }
                }
#pragma unroll
                for (int off = 32; off > 0; off >>= 1) {
                    float ox = __shfl_xor(mx, off);
                    int oi = __shfl_xor(mi, off);
                    if (ox > mx || (ox == mx && oi >= 0 && (mi < 0 || oi < mi))) { mx = ox; mi = oi; }
                }
                if (lane == 0) {
                    bsum += expf(mx - 20.0f);
                    if (mi >= 0) bnd[mi] = -3.0e38f;
                }
            }
        }
        if (pn > NEG_K) {
            // rare: 50 lowest-index positives
            for (int it = 0; it < NEG_K; it++) {
                int mn = 0x7fffffff; int mc = -1;
                for (int c = lane; c < pcap; c += 64) {
                    int ix = pidx[c];
                    if (ix < mn) { mn = ix; mc = c; }
                }
#pragma unroll
                for (int off = 32; off > 0; off >>= 1) {
                    int on = __shfl_xor(mn, off);
                    int oc = __shfl_xor(mc, off);
                    if (on < mn) { mn = on; mc = oc; }
                }
                if (lane == 0 && mc >= 0) {
                    float v = pv[mc];
                    ps += v;
                    pe += expf(v - 20.0f);
                    pidx[mc] = 0x7fffffff;
                }
            }
        }
        if (lane == 0) { w_bsum = bsum; w_ps = ps; w_pe = pe; }
    }
    __syncthreads();

    if (tid == 0) {
        float pos_e = (pn <= NEG_K) ? posexp : w_pe;
        float pos_s = (pn <= NEG_K) ? possum : w_ps;
        float totexp = negexp_above + w_bsum + pos_e;
        float lse = 20.0f + logf(totexp);
        float loss = ((float)q * lse - pos_s) / (float)max(pn, 1);
        atomicAdd(out, loss / (float)B);
    }
}

extern "C" void kernel_launch(void* const* d_in, const int* in_sizes, int n_in,
                              void* d_out, int out_size, void* d_ws, size_t ws_size,
                              hipStream_t stream) {
    const float* F  = (const float*)d_in[0];
    const int* il   = (const int*)d_in[1];
    const float* Pm = (const float*)d_in[2];
    const int* ipi  = (const int*)d_in[3];
    const int* apl  = (const int*)d_in[4];
    float* out = (float*)d_out;

    const int D = 256;
    const int B = in_sizes[0] / D;      // 256
    const int P = in_sizes[2] / D;      // 100000

    char* ws = (char*)d_ws;
    int* batch_lbl = (int*)(ws);
    int* posn  = (int*)(ws + 1024);
    int* candn = (int*)(ws + 2048);
    float* posv = (float*)(ws + 4096);
    int* posi  = (int*)(ws + 4096 + 256 * POSCAP * 4);
    float* cand = (float*)(ws + 4096 + 2 * 256 * POSCAP * 4);
    size_t scores_off = 4096 + (size_t)2 * 256 * POSCAP * 4 + (size_t)256 * CANDCAP * 4;
    scores_off = (scores_off + 255) & ~(size_t)255;
    float* scores = (float*)(ws + scores_off);

    size_t avail = (ws_size > scores_off) ? ws_size - scores_off : 0;
    size_t rowbytes = (size_t)P * 4;
    int R;
    if      (avail >= (size_t)B * rowbytes) R = B;
    else if (avail >= 128 * rowbytes)       R = 128;
    else if (avail >= 64 * rowbytes)        R = 64;
    else                                    R = 32;

    setup_kernel<<<1, 256, 0, stream>>>(il, ipi, apl, B, batch_lbl, posn, candn, out);

    int nsl = (P + SLICE - 1) / SLICE;
    for (int rb = 0; rb < B; rb += R) {
        int rc = min(R, B - rb);
        dim3 ggrid((P + 127) / 128, (rc + 127) / 128);
        gemm_bf16<<<ggrid, 256, 0, stream>>>(F, Pm, scores, rb, rc, B, P);
        dim3 sgrid(nsl, rc);
        selectA_kernel<<<sgrid, 256, 0, stream>>>(scores, apl, batch_lbl, rb, P,
                                                  posn, posv, posi, candn, cand);
    }
    final_kernel<<<B, 256, 0, stream>>>(posn, posv, posi, candn, cand, out, B);
}